// Round 1
// baseline (7422.191 us; speedup 1.0000x reference)
//
#include <hip/hip_runtime.h>
#include <hip/hip_bf16.h>
#include <hip/hip_cooperative_groups.h>

namespace cg = cooperative_groups;

typedef _Float16 f16;
typedef __attribute__((ext_vector_type(8))) _Float16 f16x8;
typedef __attribute__((ext_vector_type(4))) float f32x4;

#define NB   512
#define NI   128
#define NH   1024
#define NG   4096
#define NSEQ 96

__device__ __forceinline__ float sigm(float x)  { return 1.0f / (1.0f + __expf(-x)); }
__device__ __forceinline__ float tanhf_(float x){ return 2.0f / (1.0f + __expf(-2.0f * x)) - 1.0f; }

// Persistent cooperative LSTM decoder.
// Grid = 256 blocks x 256 threads (1 block/CU). Per step:
//   Phase A: gates GEMM (M=512,N=4096,K=1152) -> cell update (c in LDS, persistent)
//   Phase B: y = h_new @ W_fc^T + b_fc ; y feeds back as next x; y[:,127] -> out
__global__ __launch_bounds__(256)
void lstm_kernel(const float* __restrict__ xt, const float* __restrict__ hidden,
                 const float* __restrict__ cell, const float* __restrict__ W_ih,
                 const float* __restrict__ W_hh, const float* __restrict__ b_ih,
                 const float* __restrict__ b_hh, const float* __restrict__ W_fc,
                 const float* __restrict__ b_fc, float* __restrict__ out,
                 f16* __restrict__ whh, f16* __restrict__ wih,
                 f16* __restrict__ wfc, float* __restrict__ b4,
                 f16* __restrict__ xbuf, f16* __restrict__ h0,
                 f16* __restrict__ h1)
{
    cg::grid_group grid = cg::this_grid();

    __shared__ f16   ldsA[2 * 64 * 40];     // double-buffered A tile, pitch 40 (pad: 2-way max conflict)
    __shared__ float gbuf[4][64][33];       // per-gate 64x32 f32 results (pad 33: conflict-free)
    __shared__ float ctile[64][32];         // persistent cell state tile
    __shared__ float ybuf[4][16][17];       // phase-B cross-wave reduction

    const int tid = threadIdx.x;
    const int bid = blockIdx.x;
    const int gid = bid * 256 + tid;
    const int GSZ = 256 * 256;

    // ---------------- prologue: fp32 -> fp16 weights, bias sum, state init ----------------
    for (int i = gid; i < NG * NH; i += GSZ) whh[i] = (f16)W_hh[i];
    for (int i = gid; i < NG * NI; i += GSZ) wih[i] = (f16)W_ih[i];
    for (int i = gid; i < NI * NH; i += GSZ) wfc[i] = (f16)W_fc[i];
    for (int i = gid; i < NG;      i += GSZ) b4[i]  = b_ih[i] + b_hh[i];
    for (int i = gid; i < NB * NI; i += GSZ) xbuf[i] = (f16)xt[i];
    for (int i = gid; i < NB * NH; i += GSZ) h0[i]   = (f16)hidden[i];

    const int r0 = (bid >> 5) * 64;   // batch-row tile (8 tiles of 64)
    const int u0 = (bid & 31) * 32;   // hidden-unit strip (32 strips of 32)
    for (int i = tid; i < 64 * 32; i += 256)
        ctile[i >> 5][i & 31] = cell[(r0 + (i >> 5)) * NH + u0 + (i & 31)];

    grid.sync();

    const int w    = tid >> 6;   // wave 0..3 == gate type i,f,g,o
    const int lane = tid & 63;
    const int quad = lane >> 4;
    const int l16  = lane & 15;

    // A-staging role: thread -> (row, k-offset)
    const int srow = tid >> 2;         // 0..63
    const int skk  = (tid & 3) * 8;    // 0,8,16,24

    // Phase-A invariant pointers (B operand = rows of [W_ih | W_hh])
    const int n0g = w * NH + u0 + l16;                 // global gate column, nt=0
    const f16* wihp0 = wih + n0g * NI + quad * 8;
    const f16* wihp1 = wihp0 + 16 * NI;
    const f16* whhp0 = whh + n0g * NH + quad * 8;
    const f16* whhp1 = whhp0 + 16 * NH;
    const float bias0 = b4[n0g];
    const float bias1 = b4[n0g + 16];

    // Phase-B indices
    const int rb = bid >> 3, cb = bid & 7;
    const int row0 = rb * 16, col0 = cb * 16;
    const f16* wfcp = wfc + (col0 + l16) * NH + quad * 8;
    const float bfc = b_fc[col0 + (tid & 15)];

    const f16* xrow = xbuf + (r0 + srow) * NI + skk;

    for (int t = 0; t < NSEQ; ++t) {
        const f16* hin  = (t & 1) ? h1 : h0;
        f16*       hout = (t & 1) ? h0 : h1;
        const f16* hrow = hin + (r0 + srow) * NH + skk;

        // ---------------- Phase A: gates = x@W_ih^T + h@W_hh^T + b ----------------
        f32x4 acc[4][2];
#pragma unroll
        for (int mt = 0; mt < 4; ++mt) {
            acc[mt][0] = f32x4{0.f, 0.f, 0.f, 0.f};
            acc[mt][1] = f32x4{0.f, 0.f, 0.f, 0.f};
        }

        auto loadA = [&](int kb) -> f16x8 {
            const int k0 = kb * 32;
            if (k0 < NI) return *(const f16x8*)(xrow + k0);
            return *(const f16x8*)(hrow + (k0 - NI));
        };
        auto loadB0 = [&](int kb) -> f16x8 {
            const int k0 = kb * 32;
            if (k0 < NI) return *(const f16x8*)(wihp0 + k0);
            return *(const f16x8*)(whhp0 + (k0 - NI));
        };
        auto loadB1 = [&](int kb) -> f16x8 {
            const int k0 = kb * 32;
            if (k0 < NI) return *(const f16x8*)(wihp1 + k0);
            return *(const f16x8*)(whhp1 + (k0 - NI));
        };

        // software pipeline: LDS double-buffer (1 barrier/iter), prefetched A & B
        f16x8 av = loadA(0);
        *(f16x8*)(ldsA + srow * 40 + skk) = av;   // buffer 0
        av = loadA(1);
        f16x8 b0 = loadB0(0), b1 = loadB1(0);

        for (int kb = 0; kb < 36; ++kb) {
            __syncthreads();                       // ldsA[kb&1] ready
            if (kb + 1 < 36) {
                *(f16x8*)(ldsA + ((kb + 1) & 1) * 2560 + srow * 40 + skk) = av;
                av = loadA(kb + 2 < 36 ? kb + 2 : 35);
            }
            const int kn = (kb + 1 < 36) ? kb + 1 : 35;
            f16x8 nb0 = loadB0(kn);
            f16x8 nb1 = loadB1(kn);

            const f16* abase = ldsA + (kb & 1) * 2560 + l16 * 40 + quad * 8;
#pragma unroll
            for (int mt = 0; mt < 4; ++mt) {
                f16x8 afr = *(const f16x8*)(abase + mt * 640);   // 16*40
                acc[mt][0] = __builtin_amdgcn_mfma_f32_16x16x32_f16(afr, b0, acc[mt][0], 0, 0, 0);
                acc[mt][1] = __builtin_amdgcn_mfma_f32_16x16x32_f16(afr, b1, acc[mt][1], 0, 0, 0);
            }
            b0 = nb0; b1 = nb1;
        }

        // C layout: col = lane&15, row = quad*4 + reg  (per 16-tile)
#pragma unroll
        for (int mt = 0; mt < 4; ++mt) {
#pragma unroll
            for (int r = 0; r < 4; ++r) {
                gbuf[w][mt * 16 + quad * 4 + r][l16] = acc[mt][0][r] + bias0;
                gbuf[w][mt * 16 + quad * 4 + r][16 + l16] = acc[mt][1][r] + bias1;  // NOTE: cols 16..31 of strip
            }
        }
        __syncthreads();

        // cell update (c persistent in LDS; thread<->(rr,uu) mapping static across steps)
        {
            const int uu    = tid & 31;
            const int rbase = (tid >> 5) * 8;
#pragma unroll
            for (int s = 0; s < 8; ++s) {
                const int rr = rbase + s;
                const float iv = gbuf[0][rr][uu];
                const float fv = gbuf[1][rr][uu];
                const float gv = gbuf[2][rr][uu];
                const float ov = gbuf[3][rr][uu];
                const float cn = sigm(fv) * ctile[rr][uu] + sigm(iv) * tanhf_(gv);
                ctile[rr][uu] = cn;
                hout[(r0 + rr) * NH + u0 + uu] = (f16)(sigm(ov) * tanhf_(cn));
            }
        }

        grid.sync();

        // ---------------- Phase B: y = h_new @ W_fc^T + b_fc ----------------
        {
            f32x4 accB = f32x4{0.f, 0.f, 0.f, 0.f};
            const f16* hrb = hout + (row0 + l16) * NH + w * 256 + quad * 8;
#pragma unroll
            for (int i = 0; i < 8; ++i) {
                f16x8 afr = *(const f16x8*)(hrb + i * 32);
                f16x8 bfr = *(const f16x8*)(wfcp + w * 256 + i * 32);
                accB = __builtin_amdgcn_mfma_f32_16x16x32_f16(afr, bfr, accB, 0, 0, 0);
            }
#pragma unroll
            for (int r = 0; r < 4; ++r) ybuf[w][quad * 4 + r][l16] = accB[r];
        }
        __syncthreads();
        {
            const int row = tid >> 4, col = tid & 15;
            const float y = ybuf[0][row][col] + ybuf[1][row][col]
                          + ybuf[2][row][col] + ybuf[3][row][col] + bfc;
            xbuf[(row0 + row) * NI + col0 + col] = (f16)y;    // next step's x
            if (col0 + col == 127) out[(row0 + row) * NSEQ + t] = y;
        }

        grid.sync();
    }
}

extern "C" void kernel_launch(void* const* d_in, const int* in_sizes, int n_in,
                              void* d_out, int out_size, void* d_ws, size_t ws_size,
                              hipStream_t stream) {
    const float* xt     = (const float*)d_in[0];
    const float* hidden = (const float*)d_in[1];
    const float* cell   = (const float*)d_in[2];
    const float* W_ih   = (const float*)d_in[3];
    const float* W_hh   = (const float*)d_in[4];
    const float* b_ih   = (const float*)d_in[5];
    const float* b_hh   = (const float*)d_in[6];
    const float* W_fc   = (const float*)d_in[7];
    const float* b_fc   = (const float*)d_in[8];
    float* out = (float*)d_out;

    char* ws = (char*)d_ws;
    f16*   whh  = (f16*)(ws);              // 4096*1024*2 = 8,388,608
    f16*   wih  = (f16*)(ws + 8388608);    // 4096*128*2  = 1,048,576
    f16*   wfc  = (f16*)(ws + 9437184);    // 128*1024*2  =   262,144
    float* b4   = (float*)(ws + 9699328);  // 4096*4      =    16,384
    f16*   xbuf = (f16*)(ws + 9715712);    // 512*128*2   =   131,072
    f16*   h0   = (f16*)(ws + 9846784);    // 512*1024*2  = 1,048,576
    f16*   h1   = (f16*)(ws + 10895360);   // 512*1024*2  = 1,048,576  (end 11,943,936)

    void* args[] = {&xt, &hidden, &cell, &W_ih, &W_hh, &b_ih, &b_hh, &W_fc, &b_fc,
                    &out, &whh, &wih, &wfc, &b4, &xbuf, &h0, &h1};
    hipLaunchCooperativeKernel(lstm_kernel, dim3(256), dim3(256), args, 0u, stream);
}